// Round 1
// baseline (134.354 us; speedup 1.0000x reference)
//
#include <hip/hip_runtime.h>
#include <math.h>

#define EMB 512
#define NM 5
#define HID 64
#define NQ 2048
#define NP 256
// workspace layout (floats)
#define WT_OFF   0
#define WT_FLOATS (1024*320)            // WT[d][m*64+h], d in [0,1024)
#define A_OFF    (WT_OFF + WT_FLOATS)
#define A_FLOATS (NM*NQ*HID)            // A[m][q][h] = hq + b1
#define B_OFF    (A_OFF + A_FLOATS)
#define B_FLOATS (NM*16*NP*4)           // B[m][h/4][p][h%4] = hp

// ---------------------------------------------------------------------------
// Kernel 1: transpose W1 (320 x 1024) -> WT (1024 x 320), LDS-tiled.
__global__ __launch_bounds__(256) void transpose_w1(const float* __restrict__ W1,
                                                    float* __restrict__ WT) {
    __shared__ float tile[32][33];
    int bx = blockIdx.x & 31;   // d-tile   0..31
    int by = blockIdx.x >> 5;   // mh-tile  0..9
    int tx = threadIdx.x & 31;
    int ty = threadIdx.x >> 5;  // 0..7
#pragma unroll
    for (int k = 0; k < 4; ++k) {
        int r = by*32 + ty + k*8;        // mh row
        int c = bx*32 + tx;              // d col
        tile[ty + k*8][tx] = W1[r*1024 + c];
    }
    __syncthreads();
#pragma unroll
    for (int k = 0; k < 4; ++k) {
        int r = bx*32 + ty + k*8;        // d row
        int c = by*32 + tx;              // mh col
        WT[r*320 + c] = tile[tx][ty + k*8];
    }
}

// ---------------------------------------------------------------------------
// Kernel 2: phase-1 GEMMs.  Rows 0..2047 = query -> A (+b1), rows 2048..2303 =
// prototypes -> B.  Block = 8 rows x 320 output cols (mh).  X via scalar loads.
__global__ __launch_bounds__(320) void phase1(const float* __restrict__ Q,
                                              const float* __restrict__ P,
                                              const float* __restrict__ WT,
                                              const float* __restrict__ b1,
                                              float* __restrict__ A,
                                              float* __restrict__ B) {
    int t  = threadIdx.x;                 // 0..319 : mh column
    int r0 = blockIdx.x * 8;              // first row of this block
    bool isQ = (r0 < NQ);
    const float* X = isQ ? (Q + (size_t)r0 * EMB) : (P + (size_t)(r0 - NQ) * EMB);
    const float* W = isQ ? WT : (WT + 512*320);

    float acc[8] = {0,0,0,0,0,0,0,0};
#pragma unroll 4
    for (int d = 0; d < EMB; ++d) {
        float w = W[d*320 + t];           // coalesced vector load (L2-resident)
#pragma unroll
        for (int j = 0; j < 8; ++j)       // X[...] is block-uniform -> s_load
            acc[j] = fmaf(X[(size_t)j*EMB + d], w, acc[j]);
    }

    int m = t >> 6, h = t & 63;
    if (isQ) {
        float bb = b1[t];                 // t == m*64+h
#pragma unroll
        for (int j = 0; j < 8; ++j)
            A[((size_t)m*NQ + (r0 + j))*HID + h] = acc[j] + bb;
    } else {
        int p0 = r0 - NQ;
#pragma unroll
        for (int j = 0; j < 8; ++j)
            B[(((m*16 + (h >> 2))*NP + (p0 + j)) << 2) + (h & 3)] = acc[j];
    }
}

// ---------------------------------------------------------------------------
// Kernel 3: fused relu-ensemble + mean/std/exp.
// Block = 256 threads = 4 waves. Each thread: 4 q (wave-uniform, scalar A/W2)
// x 1 p (lane). B held in 64 VGPRs per model, coalesced dwordx4 reloads.
__global__ __launch_bounds__(256) void fused_main(const float* __restrict__ A,
                                                  const float* __restrict__ Bv,
                                                  const float* __restrict__ W2,
                                                  const float* __restrict__ b2,
                                                  float* __restrict__ out) {
    int tid  = threadIdx.x;
    int lane = tid & 63;
    int wave = tid >> 6;
    int p    = wave*64 + lane;            // 0..255
    int qbase = blockIdx.x * 4;

    float s1[4] = {0,0,0,0};
    float s2[4] = {0,0,0,0};

#pragma unroll 1
    for (int m = 0; m < NM; ++m) {
        float4 Bf[16];
#pragma unroll
        for (int hc = 0; hc < 16; ++hc)
            Bf[hc] = *(const float4*)&Bv[(((m*16 + hc)*NP + p) << 2)];

        const float* Arow = A + ((size_t)m*NQ + qbase)*HID;   // uniform
        const float* w2r  = W2 + m*HID;                       // uniform
        float o[4] = {0,0,0,0};
#pragma unroll
        for (int hc = 0; hc < 16; ++hc) {
            const float* bf = (const float*)&Bf[hc];
#pragma unroll
            for (int hl = 0; hl < 4; ++hl) {
                int h = hc*4 + hl;
                float w = w2r[h];          // uniform -> SGPR
                float b = bf[hl];
#pragma unroll
                for (int j = 0; j < 4; ++j) {
                    float v = Arow[j*HID + h] + b;   // v_add (1 sgpr)
                    v = fmaxf(v, 0.f);               // v_max inline 0
                    o[j] = fmaf(v, w, o[j]);         // v_fmac (1 sgpr)
                }
            }
        }
        float bb2 = b2[m];
#pragma unroll
        for (int j = 0; j < 4; ++j) {
            float oo = o[j] + bb2;
            s1[j] += oo;
            s2[j] = fmaf(oo, oo, s2[j]);
        }
    }

#pragma unroll
    for (int j = 0; j < 4; ++j) {
        float mean = s1[j] * 0.2f;
        float var  = (s2[j] - s1[j]*s1[j]*0.2f) * 0.25f;
        var = fmaxf(var, 0.f);
        float unc = sqrtf(var);
        out[(size_t)(qbase + j)*NP + p] = mean * __expf(-unc);
    }
}

// ---------------------------------------------------------------------------
extern "C" void kernel_launch(void* const* d_in, const int* in_sizes, int n_in,
                              void* d_out, int out_size, void* d_ws, size_t ws_size,
                              hipStream_t stream) {
    const float* Q  = (const float*)d_in[0];   // (2048, 512)
    const float* P  = (const float*)d_in[1];   // (256, 512)
    const float* W1 = (const float*)d_in[2];   // (5, 64, 1024)
    const float* b1 = (const float*)d_in[3];   // (5, 64)
    const float* W2 = (const float*)d_in[4];   // (5, 64)
    const float* b2 = (const float*)d_in[5];   // (5,)
    float* out = (float*)d_out;

    float* ws = (float*)d_ws;
    float* WT = ws + WT_OFF;
    float* A  = ws + A_OFF;
    float* B  = ws + B_OFF;

    transpose_w1<<<320, 256, 0, stream>>>(W1, WT);
    phase1<<<(NQ + NP) / 8, 320, 0, stream>>>(Q, P, WT, b1, A, B);
    fused_main<<<NQ / 4, 256, 0, stream>>>(A, B, W2, b2, out);
}

// Round 2
// 121.864 us; speedup vs baseline: 1.1025x; 1.1025x over previous
//
#include <hip/hip_runtime.h>
#include <math.h>

#define EMB 512
#define NM 5
#define HID 64
#define NQ 2048
#define NP 256
#define MH 320              // NM*HID
#define NROWS (NQ + NP)     // 2304
#define KSPLIT 4

// ws layout (floats)
#define WT_OFF   0
#define WT_FLOATS (1024 * MH)                  // float4-transposed W1: [256 d4][320 t][4]
#define PART_OFF (WT_OFF + WT_FLOATS)
#define PART_FLOATS (KSPLIT * NROWS * MH)      // partial sums per K-chunk
#define A_OFF    (PART_OFF + PART_FLOATS)
#define A_FLOATS (NM * NQ * HID)               // A[m][q][h] = hq + b1
#define B_OFF    (A_OFF + A_FLOATS)
#define B_FLOATS (NM * 16 * NP * 4)            // B[m][h/4][p][h%4] = hp

// ---------------------------------------------------------------------------
// Kernel 1: float4-granular transpose. W1 viewed as float4 [320][256] ->
// WT4 float4 [256][320].  Thread t in phase1 then loads one float4 =
// W1[t][4d4..4d4+3] per K-step, fully coalesced 16B/lane.
__global__ __launch_bounds__(256) void transpose_w1(const float* __restrict__ W1,
                                                    float* __restrict__ WT4) {
    const float4* in  = (const float4*)W1;   // [320][256]
    float4*       out = (float4*)WT4;        // [256][320]
    __shared__ float4 tile[32][33];
    int bx = blockIdx.x % 10;    // t-tile  (320/32)
    int by = blockIdx.x / 10;    // d4-tile (256/32)
    int tx = threadIdx.x & 31, ty = threadIdx.x >> 5;
#pragma unroll
    for (int k = 0; k < 4; ++k)
        tile[ty + k*8][tx] = in[(bx*32 + ty + k*8)*256 + by*32 + tx];
    __syncthreads();
#pragma unroll
    for (int k = 0; k < 4; ++k)
        out[(by*32 + ty + k*8)*320 + bx*32 + tx] = tile[tx][ty + k*8];
}

// ---------------------------------------------------------------------------
// Kernel 2: phase-1 GEMM with K-split x4.  blockIdx = rowblock*4 + kc.
// 8 rows x 320 cols (t = m*64+h), 128-d K-chunk.  W via float4 (16B/lane),
// X via wave-uniform scalar loads.  Partials to ws.
__global__ __launch_bounds__(320) void phase1(const float* __restrict__ Q,
                                              const float* __restrict__ P,
                                              const float* __restrict__ WT4,
                                              float* __restrict__ part) {
    int t  = threadIdx.x;
    int rb = blockIdx.x >> 2;
    int kc = blockIdx.x & 3;
    int r0 = rb * 8;
    bool isQ = (r0 < NQ);
    const float*  X  = isQ ? (Q + (size_t)r0 * EMB) : (P + (size_t)(r0 - NQ) * EMB);
    int d4base = (isQ ? 0 : 128) + kc * 32;          // float4 index into 1024-wide W1 row
    const float4* Wf = (const float4*)WT4 + (size_t)d4base * MH + t;

    float acc[8] = {0,0,0,0,0,0,0,0};
#pragma unroll 4
    for (int i = 0; i < 32; ++i) {
        float4 w = Wf[(size_t)i * MH];
        int d = (kc*32 + i) * 4;                     // offset within 512-wide X row
#pragma unroll
        for (int j = 0; j < 8; ++j) {
            acc[j] = fmaf(X[j*EMB + d + 0], w.x, acc[j]);
            acc[j] = fmaf(X[j*EMB + d + 1], w.y, acc[j]);
            acc[j] = fmaf(X[j*EMB + d + 2], w.z, acc[j]);
            acc[j] = fmaf(X[j*EMB + d + 3], w.w, acc[j]);
        }
    }
    float* pp = part + ((size_t)kc * NROWS + r0) * MH + t;
#pragma unroll
    for (int j = 0; j < 8; ++j) pp[j*MH] = acc[j];
}

// ---------------------------------------------------------------------------
// Kernel 3: reduce K-split partials, add b1, route to A / blocked-B layouts.
__global__ __launch_bounds__(320) void reduce_k(const float* __restrict__ part,
                                                const float* __restrict__ b1,
                                                float* __restrict__ A,
                                                float* __restrict__ B) {
    int row = blockIdx.x, t = threadIdx.x;
    float s = 0.f;
#pragma unroll
    for (int kc = 0; kc < KSPLIT; ++kc)
        s += part[((size_t)kc * NROWS + row) * MH + t];
    int m = t >> 6, h = t & 63;
    if (row < NQ) {
        A[((size_t)m*NQ + row)*HID + h] = s + b1[t];
    } else {
        int p = row - NQ;
        B[(((m*16 + (h >> 2))*NP + p) << 2) + (h & 3)] = s;
    }
}

// ---------------------------------------------------------------------------
// Kernel 4: fused relu-ensemble + mean/std/exp.  2 q per thread -> grid 1024
// blocks (4 blocks/CU, 16 waves/CU).  B in 64 VGPRs/model via coalesced
// dwordx4; A & W2 wave-uniform -> scalar path.
__global__ __launch_bounds__(256) void fused_main(const float* __restrict__ A,
                                                  const float* __restrict__ Bv,
                                                  const float* __restrict__ W2,
                                                  const float* __restrict__ b2,
                                                  float* __restrict__ out) {
    int p  = threadIdx.x;            // 0..255
    int q0 = blockIdx.x * 2;

    float s1[2] = {0,0};
    float s2[2] = {0,0};

#pragma unroll 1
    for (int m = 0; m < NM; ++m) {
        float4 Bf[16];
#pragma unroll
        for (int hc = 0; hc < 16; ++hc)
            Bf[hc] = *(const float4*)&Bv[(((m*16 + hc)*NP + p) << 2)];

        const float* Arow = A + ((size_t)m*NQ + q0)*HID;   // block-uniform
        const float* w2r  = W2 + m*HID;                    // block-uniform
        float o[2] = {0,0};
#pragma unroll
        for (int hc = 0; hc < 16; ++hc) {
            const float* bf = (const float*)&Bf[hc];
#pragma unroll
            for (int hl = 0; hl < 4; ++hl) {
                int h = hc*4 + hl;
                float w = w2r[h];
                float b = bf[hl];
#pragma unroll
                for (int j = 0; j < 2; ++j) {
                    float v = fmaxf(Arow[j*HID + h] + b, 0.f);
                    o[j] = fmaf(v, w, o[j]);
                }
            }
        }
        float bb2 = b2[m];
#pragma unroll
        for (int j = 0; j < 2; ++j) {
            float oo = o[j] + bb2;
            s1[j] += oo;
            s2[j] = fmaf(oo, oo, s2[j]);
        }
    }

#pragma unroll
    for (int j = 0; j < 2; ++j) {
        float mean = s1[j] * 0.2f;
        float var  = fmaxf((s2[j] - s1[j]*s1[j]*0.2f) * 0.25f, 0.f);
        out[(size_t)(q0 + j)*NP + p] = mean * __expf(-sqrtf(var));
    }
}

// ---------------------------------------------------------------------------
extern "C" void kernel_launch(void* const* d_in, const int* in_sizes, int n_in,
                              void* d_out, int out_size, void* d_ws, size_t ws_size,
                              hipStream_t stream) {
    const float* Q  = (const float*)d_in[0];   // (2048, 512)
    const float* P  = (const float*)d_in[1];   // (256, 512)
    const float* W1 = (const float*)d_in[2];   // (5, 64, 1024)
    const float* b1 = (const float*)d_in[3];   // (5, 64)
    const float* W2 = (const float*)d_in[4];   // (5, 64)
    const float* b2 = (const float*)d_in[5];   // (5,)
    float* out = (float*)d_out;

    float* ws   = (float*)d_ws;
    float* WT4  = ws + WT_OFF;
    float* part = ws + PART_OFF;
    float* A    = ws + A_OFF;
    float* B    = ws + B_OFF;

    transpose_w1<<<80, 256, 0, stream>>>(W1, WT4);
    phase1<<<(NROWS/8) * KSPLIT, 320, 0, stream>>>(Q, P, WT4, part);
    reduce_k<<<NROWS, 320, 0, stream>>>(part, b1, A, B);
    fused_main<<<NQ/2, 256, 0, stream>>>(A, B, W2, b2, out);
}

// Round 3
// 118.721 us; speedup vs baseline: 1.1317x; 1.0265x over previous
//
#include <hip/hip_runtime.h>
#include <math.h>

#define EMB 512
#define NM 5
#define HID 64
#define NQ 2048
#define NP 256
#define MH 320              // NM*HID
#define NROWS (NQ + NP)     // 2304
#define KSPLIT 4

// ws layout (floats)
#define WT_OFF   0
#define WT_FLOATS (1024 * MH)                  // float4-transposed W1: [256 d4][320 t][4]
#define PART_OFF (WT_OFF + WT_FLOATS)
#define PART_FLOATS (KSPLIT * NROWS * MH)
#define A_OFF    (PART_OFF + PART_FLOATS)
#define A_FLOATS (NM * NQ * HID)               // A[m][q][h] = hq + b1
#define B_OFF    (A_OFF + A_FLOATS)
#define B_FLOATS (NM * 16 * NP * 4)            // B[m][h/4][p][h%4] = hp

// ---------------------------------------------------------------------------
// Kernel 1: float4-granular transpose of W1 ([320][256] f4 -> [256][320] f4).
__global__ __launch_bounds__(256) void transpose_w1(const float* __restrict__ W1,
                                                    float* __restrict__ WT4) {
    const float4* in  = (const float4*)W1;
    float4*       out = (float4*)WT4;
    __shared__ float4 tile[32][33];
    int bx = blockIdx.x % 10;    // t-tile
    int by = blockIdx.x / 10;    // d4-tile
    int tx = threadIdx.x & 31, ty = threadIdx.x >> 5;
#pragma unroll
    for (int k = 0; k < 4; ++k)
        tile[ty + k*8][tx] = in[(bx*32 + ty + k*8)*256 + by*32 + tx];
    __syncthreads();
#pragma unroll
    for (int k = 0; k < 4; ++k)
        out[(by*32 + ty + k*8)*320 + bx*32 + tx] = tile[tx][ty + k*8];
}

// ---------------------------------------------------------------------------
// Kernel 2: phase-1 GEMM, K-split x4, manual depth-4 register rotation on the
// W float4 stream so 64 B/lane stay in flight through each FMA group.
// X (rows) through the scalar path (block-uniform addresses).
#define SUBSTEP(W4, DD) \
    a0 = fmaf(X[0*EMB+(DD)+0], W4.x, a0); a0 = fmaf(X[0*EMB+(DD)+1], W4.y, a0); \
    a0 = fmaf(X[0*EMB+(DD)+2], W4.z, a0); a0 = fmaf(X[0*EMB+(DD)+3], W4.w, a0); \
    a1 = fmaf(X[1*EMB+(DD)+0], W4.x, a1); a1 = fmaf(X[1*EMB+(DD)+1], W4.y, a1); \
    a1 = fmaf(X[1*EMB+(DD)+2], W4.z, a1); a1 = fmaf(X[1*EMB+(DD)+3], W4.w, a1); \
    a2 = fmaf(X[2*EMB+(DD)+0], W4.x, a2); a2 = fmaf(X[2*EMB+(DD)+1], W4.y, a2); \
    a2 = fmaf(X[2*EMB+(DD)+2], W4.z, a2); a2 = fmaf(X[2*EMB+(DD)+3], W4.w, a2); \
    a3 = fmaf(X[3*EMB+(DD)+0], W4.x, a3); a3 = fmaf(X[3*EMB+(DD)+1], W4.y, a3); \
    a3 = fmaf(X[3*EMB+(DD)+2], W4.z, a3); a3 = fmaf(X[3*EMB+(DD)+3], W4.w, a3); \
    a4 = fmaf(X[4*EMB+(DD)+0], W4.x, a4); a4 = fmaf(X[4*EMB+(DD)+1], W4.y, a4); \
    a4 = fmaf(X[4*EMB+(DD)+2], W4.z, a4); a4 = fmaf(X[4*EMB+(DD)+3], W4.w, a4); \
    a5 = fmaf(X[5*EMB+(DD)+0], W4.x, a5); a5 = fmaf(X[5*EMB+(DD)+1], W4.y, a5); \
    a5 = fmaf(X[5*EMB+(DD)+2], W4.z, a5); a5 = fmaf(X[5*EMB+(DD)+3], W4.w, a5); \
    a6 = fmaf(X[6*EMB+(DD)+0], W4.x, a6); a6 = fmaf(X[6*EMB+(DD)+1], W4.y, a6); \
    a6 = fmaf(X[6*EMB+(DD)+2], W4.z, a6); a6 = fmaf(X[6*EMB+(DD)+3], W4.w, a6); \
    a7 = fmaf(X[7*EMB+(DD)+0], W4.x, a7); a7 = fmaf(X[7*EMB+(DD)+1], W4.y, a7); \
    a7 = fmaf(X[7*EMB+(DD)+2], W4.z, a7); a7 = fmaf(X[7*EMB+(DD)+3], W4.w, a7);

__global__ __launch_bounds__(320) void phase1(const float* __restrict__ Q,
                                              const float* __restrict__ P,
                                              const float* __restrict__ WT4,
                                              float* __restrict__ part) {
    int t  = threadIdx.x;
    int rb = blockIdx.x >> 2;
    int kc = blockIdx.x & 3;
    int r0 = rb * 8;
    bool isQ = (r0 < NQ);
    const float*  X  = isQ ? (Q + (size_t)r0 * EMB) : (P + (size_t)(r0 - NQ) * EMB);
    int d4base = (isQ ? 0 : 128) + kc * 32;
    const float4* Wf = (const float4*)WT4 + (size_t)d4base * MH + t;
    int d0 = kc * 128;                     // float offset into X rows

    float a0=0,a1=0,a2=0,a3=0,a4=0,a5=0,a6=0,a7=0;

    float4 c0 = Wf[0*MH], c1 = Wf[1*MH], c2 = Wf[2*MH], c3 = Wf[3*MH];
#pragma unroll 1
    for (int i = 0; i < 28; i += 4) {
        float4 n0 = Wf[(size_t)(i+4)*MH];
        float4 n1 = Wf[(size_t)(i+5)*MH];
        float4 n2 = Wf[(size_t)(i+6)*MH];
        float4 n3 = Wf[(size_t)(i+7)*MH];
        int dd = d0 + i*4;
        SUBSTEP(c0, dd)
        SUBSTEP(c1, dd+4)
        SUBSTEP(c2, dd+8)
        SUBSTEP(c3, dd+12)
        c0 = n0; c1 = n1; c2 = n2; c3 = n3;
    }
    {
        int dd = d0 + 112;
        SUBSTEP(c0, dd)
        SUBSTEP(c1, dd+4)
        SUBSTEP(c2, dd+8)
        SUBSTEP(c3, dd+12)
    }

    float* pp = part + ((size_t)kc * NROWS + r0) * MH + t;
    pp[0*MH]=a0; pp[1*MH]=a1; pp[2*MH]=a2; pp[3*MH]=a3;
    pp[4*MH]=a4; pp[5*MH]=a5; pp[6*MH]=a6; pp[7*MH]=a7;
}

// ---------------------------------------------------------------------------
// Kernel 3: reduce K-split partials, add b1, route to A / blocked-B layouts.
__global__ __launch_bounds__(320) void reduce_k(const float* __restrict__ part,
                                                const float* __restrict__ b1,
                                                float* __restrict__ A,
                                                float* __restrict__ B) {
    int row = blockIdx.x, t = threadIdx.x;
    float s = 0.f;
#pragma unroll
    for (int kc = 0; kc < KSPLIT; ++kc)
        s += part[((size_t)kc * NROWS + row) * MH + t];
    int m = t >> 6, h = t & 63;
    if (row < NQ) {
        A[((size_t)m*NQ + row)*HID + h] = s + b1[t];
    } else {
        int p = row - NQ;
        B[(((m*16 + (h >> 2))*NP + p) << 2) + (h & 3)] = s;
    }
}

// ---------------------------------------------------------------------------
// Kernel 4: fused relu-ensemble + mean/std/exp.  NO address-taken arrays —
// 16 named float4 regs per model (B), A/W2 via scalar path.  2 q per thread.
__global__ __launch_bounds__(256) void fused_main(const float* __restrict__ A,
                                                  const float* __restrict__ Bv,
                                                  const float* __restrict__ W2,
                                                  const float* __restrict__ b2,
                                                  float* __restrict__ out) {
    int p  = threadIdx.x;            // 0..255
    int q0 = blockIdx.x * 2;

    float s1a=0, s2a=0, s1b=0, s2b=0;
    const float4* Bq = (const float4*)Bv + p;

#pragma unroll 1
    for (int m = 0; m < NM; ++m) {
        const float4* bm = Bq + (size_t)m * 16 * NP;
        float4 B0 = bm[0*NP],  B1 = bm[1*NP],  B2 = bm[2*NP],  B3 = bm[3*NP];
        float4 B4 = bm[4*NP],  B5 = bm[5*NP],  B6 = bm[6*NP],  B7 = bm[7*NP];
        float4 B8 = bm[8*NP],  B9 = bm[9*NP],  B10= bm[10*NP], B11= bm[11*NP];
        float4 B12= bm[12*NP], B13= bm[13*NP], B14= bm[14*NP], B15= bm[15*NP];

        const float* Ar = A + ((size_t)m*NQ + q0)*HID;   // block-uniform
        const float* Wp = W2 + m*HID;                    // block-uniform
        float oa = 0.f, ob = 0.f;

#define HSTEP(BF, H0) { \
        float wa=Wp[H0+0], wb=Wp[H0+1], wc=Wp[H0+2], wd=Wp[H0+3]; \
        oa = fmaf(fmaxf(Ar[H0+0]    + BF.x, 0.f), wa, oa); \
        oa = fmaf(fmaxf(Ar[H0+1]    + BF.y, 0.f), wb, oa); \
        oa = fmaf(fmaxf(Ar[H0+2]    + BF.z, 0.f), wc, oa); \
        oa = fmaf(fmaxf(Ar[H0+3]    + BF.w, 0.f), wd, oa); \
        ob = fmaf(fmaxf(Ar[64+H0+0] + BF.x, 0.f), wa, ob); \
        ob = fmaf(fmaxf(Ar[64+H0+1] + BF.y, 0.f), wb, ob); \
        ob = fmaf(fmaxf(Ar[64+H0+2] + BF.z, 0.f), wc, ob); \
        ob = fmaf(fmaxf(Ar[64+H0+3] + BF.w, 0.f), wd, ob); }

        HSTEP(B0,  0)  HSTEP(B1,  4)  HSTEP(B2,  8)  HSTEP(B3, 12)
        HSTEP(B4, 16)  HSTEP(B5, 20)  HSTEP(B6, 24)  HSTEP(B7, 28)
        HSTEP(B8, 32)  HSTEP(B9, 36)  HSTEP(B10,40)  HSTEP(B11,44)
        HSTEP(B12,48)  HSTEP(B13,52)  HSTEP(B14,56)  HSTEP(B15,60)
#undef HSTEP

        float bb = b2[m];
        float xa = oa + bb, xb = ob + bb;
        s1a += xa; s2a = fmaf(xa, xa, s2a);
        s1b += xb; s2b = fmaf(xb, xb, s2b);
    }

    {
        float mean = s1a * 0.2f;
        float var  = fmaxf((s2a - s1a*s1a*0.2f) * 0.25f, 0.f);
        out[(size_t)q0*NP + p] = mean * __expf(-sqrtf(var));
    }
    {
        float mean = s1b * 0.2f;
        float var  = fmaxf((s2b - s1b*s1b*0.2f) * 0.25f, 0.f);
        out[(size_t)(q0+1)*NP + p] = mean * __expf(-sqrtf(var));
    }
}

// ---------------------------------------------------------------------------
extern "C" void kernel_launch(void* const* d_in, const int* in_sizes, int n_in,
                              void* d_out, int out_size, void* d_ws, size_t ws_size,
                              hipStream_t stream) {
    const float* Q  = (const float*)d_in[0];
    const float* P  = (const float*)d_in[1];
    const float* W1 = (const float*)d_in[2];
    const float* b1 = (const float*)d_in[3];
    const float* W2 = (const float*)d_in[4];
    const float* b2 = (const float*)d_in[5];
    float* out = (float*)d_out;

    float* ws   = (float*)d_ws;
    float* WT4  = ws + WT_OFF;
    float* part = ws + PART_OFF;
    float* A    = ws + A_OFF;
    float* B    = ws + B_OFF;

    transpose_w1<<<80, 256, 0, stream>>>(W1, WT4);
    phase1<<<(NROWS/8) * KSPLIT, 320, 0, stream>>>(Q, P, WT4, part);
    reduce_k<<<NROWS, 320, 0, stream>>>(part, b1, A, B);
    fused_main<<<NQ/2, 256, 0, stream>>>(A, B, W2, b2, out);
}

// Round 5
// 116.686 us; speedup vs baseline: 1.1514x; 1.0174x over previous
//
#include <hip/hip_runtime.h>
#include <math.h>

#define EMB 512
#define NM 5
#define HID 64
#define NQ 2048
#define NP 256

// ws layout (floats)
#define A_OFF 0
#define A_FLOATS (NM * NQ * HID)          // A[m][q][h] = hq + b1
#define B_OFF A_FLOATS                    // B[m][h/4][p][h%4] = hp

// ---------------------------------------------------------------------------
// Kernel 1: fused transpose-free phase-1 GEMM.
// lane = row (q or p), h via wave => W1 reads are wave-uniform (scalar path,
// no transpose kernel needed). X rows staged in LDS (double-buffered, pad 33,
// conflict-free b32 reads). 720 blocks: rb = bid/20 (64-row block, 0..35),
// m = (bid>>2)%5, hg = bid&3; wave w covers h = hg*16 + w*4 + {0..3}.
// Writes A (+b1) and blocked B directly — no K-split, no reduce kernel.
__global__ __launch_bounds__(256) void gemmAB(const float* __restrict__ Q,
                                              const float* __restrict__ P,
                                              const float* __restrict__ W1,
                                              const float* __restrict__ b1,
                                              float* __restrict__ A,
                                              float* __restrict__ Bv) {
    __shared__ float xs[2][64 * 33];
    int tid  = threadIdx.x;
    int lane = tid & 63;
    int hg   = blockIdx.x & 3;
    int m    = (blockIdx.x >> 2) % 5;
    int rb   = blockIdx.x / 20;
    int h0   = __builtin_amdgcn_readfirstlane(hg * 16 + (tid >> 6) * 4);
    bool isQ = rb < 32;
    const float* X  = isQ ? (Q + (size_t)rb * 64 * EMB)
                          : (P + (size_t)(rb - 32) * 64 * EMB);
    const float* Wr = W1 + ((size_t)m * 64 + h0) * 1024 + (isQ ? 0 : EMB);

    int row_l = tid >> 3;          // 0..31 (plus +32 second pass)
    int dl4   = (tid & 7) * 4;     // float offset within 32-d chunk

    // stage chunk 0
    {
        float4 v0 = *(const float4*)&X[(size_t)row_l        * EMB + dl4];
        float4 v1 = *(const float4*)&X[(size_t)(row_l + 32) * EMB + dl4];
        float* s0 = &xs[0][row_l * 33 + dl4];
        s0[0] = v0.x; s0[1] = v0.y; s0[2] = v0.z; s0[3] = v0.w;
        float* s1 = &xs[0][(row_l + 32) * 33 + dl4];
        s1[0] = v1.x; s1[1] = v1.y; s1[2] = v1.z; s1[3] = v1.w;
    }
    __syncthreads();

    float a0 = 0, a1 = 0, a2 = 0, a3 = 0;
#pragma unroll 1
    for (int c = 0; c < 16; ++c) {
        int cur = c & 1;
        if (c < 15) {                       // prefetch chunk c+1 into other buf
            int dn = (c + 1) * 32;
            float4 v0 = *(const float4*)&X[(size_t)row_l        * EMB + dn + dl4];
            float4 v1 = *(const float4*)&X[(size_t)(row_l + 32) * EMB + dn + dl4];
            float* s0 = &xs[cur ^ 1][row_l * 33 + dl4];
            s0[0] = v0.x; s0[1] = v0.y; s0[2] = v0.z; s0[3] = v0.w;
            float* s1 = &xs[cur ^ 1][(row_l + 32) * 33 + dl4];
            s1[0] = v1.x; s1[1] = v1.y; s1[2] = v1.z; s1[3] = v1.w;
        }
        const float* w0 = Wr + 0 * 1024 + c * 32;   // wave-uniform -> s_load
        const float* w1 = Wr + 1 * 1024 + c * 32;
        const float* w2 = Wr + 2 * 1024 + c * 32;
        const float* w3 = Wr + 3 * 1024 + c * 32;
        const float* xl = &xs[cur][lane * 33];
#pragma unroll
        for (int d = 0; d < 32; ++d) {
            float x = xl[d];                        // ds_read_b32, conflict-free
            a0 = fmaf(x, w0[d], a0);
            a1 = fmaf(x, w1[d], a1);
            a2 = fmaf(x, w2[d], a2);
            a3 = fmaf(x, w3[d], a3);
        }
        __syncthreads();
    }

    if (isQ) {
        int q = rb * 64 + lane;
        float4 o = { a0 + b1[m * 64 + h0 + 0], a1 + b1[m * 64 + h0 + 1],
                     a2 + b1[m * 64 + h0 + 2], a3 + b1[m * 64 + h0 + 3] };
        *(float4*)&A[((size_t)m * NQ + q) * HID + h0] = o;
    } else {
        int p = (rb - 32) * 64 + lane;
        float4 o = { a0, a1, a2, a3 };
        *(float4*)&Bv[(((size_t)(m * 16) + (h0 >> 2)) * NP + p) * 4] = o;   // coalesced
    }
}

// ---------------------------------------------------------------------------
// Kernel 2: fused relu-ensemble + mean/std/exp (R3 version — known-good).
__global__ __launch_bounds__(256) void fused_main(const float* __restrict__ A,
                                                  const float* __restrict__ Bv,
                                                  const float* __restrict__ W2,
                                                  const float* __restrict__ b2,
                                                  float* __restrict__ out) {
    int p  = threadIdx.x;            // 0..255
    int q0 = blockIdx.x * 2;

    float s1a = 0, s2a = 0, s1b = 0, s2b = 0;
    const float4* Bq = (const float4*)Bv + p;

#pragma unroll 1
    for (int m = 0; m < NM; ++m) {
        const float4* bm = Bq + (size_t)m * 16 * NP;
        float4 B0 = bm[0*NP],  B1 = bm[1*NP],  B2 = bm[2*NP],  B3 = bm[3*NP];
        float4 B4 = bm[4*NP],  B5 = bm[5*NP],  B6 = bm[6*NP],  B7 = bm[7*NP];
        float4 B8 = bm[8*NP],  B9 = bm[9*NP],  B10= bm[10*NP], B11= bm[11*NP];
        float4 B12= bm[12*NP], B13= bm[13*NP], B14= bm[14*NP], B15= bm[15*NP];

        const float* Ar  = A + ((size_t)m * NQ + q0) * HID;   // block-uniform
        const float* Wp2 = W2 + m * HID;                      // block-uniform
        float oa = 0.f, ob = 0.f;

#define HSTEP(BF, H0) { \
        float wa=Wp2[H0+0], wb=Wp2[H0+1], wc=Wp2[H0+2], wd=Wp2[H0+3]; \
        oa = fmaf(fmaxf(Ar[H0+0]    + BF.x, 0.f), wa, oa); \
        oa = fmaf(fmaxf(Ar[H0+1]    + BF.y, 0.f), wb, oa); \
        oa = fmaf(fmaxf(Ar[H0+2]    + BF.z, 0.f), wc, oa); \
        oa = fmaf(fmaxf(Ar[H0+3]    + BF.w, 0.f), wd, oa); \
        ob = fmaf(fmaxf(Ar[64+H0+0] + BF.x, 0.f), wa, ob); \
        ob = fmaf(fmaxf(Ar[64+H0+1] + BF.y, 0.f), wb, ob); \
        ob = fmaf(fmaxf(Ar[64+H0+2] + BF.z, 0.f), wc, ob); \
        ob = fmaf(fmaxf(Ar[64+H0+3] + BF.w, 0.f), wd, ob); }

        HSTEP(B0,  0)  HSTEP(B1,  4)  HSTEP(B2,  8)  HSTEP(B3, 12)
        HSTEP(B4, 16)  HSTEP(B5, 20)  HSTEP(B6, 24)  HSTEP(B7, 28)
        HSTEP(B8, 32)  HSTEP(B9, 36)  HSTEP(B10,40)  HSTEP(B11,44)
        HSTEP(B12,48)  HSTEP(B13,52)  HSTEP(B14,56)  HSTEP(B15,60)
#undef HSTEP

        float bb = b2[m];
        float xa = oa + bb, xb = ob + bb;
        s1a += xa; s2a = fmaf(xa, xa, s2a);
        s1b += xb; s2b = fmaf(xb, xb, s2b);
    }

    {
        float mean = s1a * 0.2f;
        float var  = fmaxf((s2a - s1a * s1a * 0.2f) * 0.25f, 0.f);
        out[(size_t)q0 * NP + p] = mean * __expf(-sqrtf(var));
    }
    {
        float mean = s1b * 0.2f;
        float var  = fmaxf((s2b - s1b * s1b * 0.2f) * 0.25f, 0.f);
        out[(size_t)(q0 + 1) * NP + p] = mean * __expf(-sqrtf(var));
    }
}

// ---------------------------------------------------------------------------
extern "C" void kernel_launch(void* const* d_in, const int* in_sizes, int n_in,
                              void* d_out, int out_size, void* d_ws, size_t ws_size,
                              hipStream_t stream) {
    const float* Q  = (const float*)d_in[0];   // (2048, 512)
    const float* P  = (const float*)d_in[1];   // (256, 512)
    const float* W1 = (const float*)d_in[2];   // (5, 64, 1024)
    const float* b1 = (const float*)d_in[3];   // (5, 64)
    const float* W2 = (const float*)d_in[4];   // (5, 64)
    const float* b2 = (const float*)d_in[5];   // (5,)
    float* out = (float*)d_out;

    float* ws = (float*)d_ws;
    float* A  = ws + A_OFF;
    float* B  = ws + B_OFF;

    gemmAB<<<720, 256, 0, stream>>>(Q, P, W1, b1, A, B);
    fused_main<<<NQ / 2, 256, 0, stream>>>(A, B, W2, b2, out);
}